// Round 3
// baseline (573.225 us; speedup 1.0000x reference)
//
#include <hip/hip_runtime.h>

#define CS 128   // chunk size
#define DH 64    // head dim
#define DS 128   // state dim
#define NC 32    // num chunks
#define NBH 64   // B*H
#define SEQ 4096

typedef __attribute__((ext_vector_type(8))) short short8;
typedef __attribute__((ext_vector_type(4))) float f32x4;

// split fp32 into bf16 hi (truncate) + bf16 lo (truncate of remainder).
__device__ __forceinline__ void bsplit(float x, short &h, short &l) {
  unsigned u = __float_as_uint(x);
  h = (short)(unsigned short)(u >> 16);
  float r = x - __uint_as_float(u & 0xffff0000u);
  l = (short)(unsigned short)(__float_as_uint(r) >> 16);
}

__device__ __forceinline__ void split8(const float4 v0, const float4 v1, short8 &h, short8 &l) {
  short hh, ll;
  bsplit(v0.x,hh,ll); h[0]=hh; l[0]=ll;
  bsplit(v0.y,hh,ll); h[1]=hh; l[1]=ll;
  bsplit(v0.z,hh,ll); h[2]=hh; l[2]=ll;
  bsplit(v0.w,hh,ll); h[3]=hh; l[3]=ll;
  bsplit(v1.x,hh,ll); h[4]=hh; l[4]=ll;
  bsplit(v1.y,hh,ll); h[5]=hh; l[5]=ll;
  bsplit(v1.z,hh,ll); h[6]=hh; l[6]=ll;
  bsplit(v1.w,hh,ll); h[7]=hh; l[7]=ll;
}

// ---------------- Phase 1: hT[d][s] = sum_t X[t][d] * dte[t] * B[t][s]  (MFMA bf16x3, no LDS, no barriers) ----------------
__global__ __launch_bounds__(256, 4) void p1_hcontrib(
    const float* __restrict__ A, const float* __restrict__ X,
    const float* __restrict__ B, float* __restrict__ hbuf,
    float* __restrict__ dtot)
{
  const int blk = blockIdx.x;
  const int bh  = blk >> 5;
  const int c   = blk & 31;
  const int tid = threadIdx.x;
  const int lane = tid & 63, w = tid >> 6;
  const int g4 = lane >> 4, l15 = lane & 15;
  const int w32 = w * 32;

  const float* Ac = A + bh * SEQ + c * CS;
  const float* Xc = X + (size_t)(bh * SEQ + c * CS) * DH;
  const float* Bc = B + (size_t)(bh * SEQ + c * CS) * DS;
  float* hout = hbuf + (size_t)blk * DS * DH;   // transposed: [DH][DS]

  // wave-level inclusive cumsum of Ac[0..127]: a0 = csum[lane], a1 = csum[64+lane]
  float a0 = Ac[lane], a1 = Ac[64 + lane];
#pragma unroll
  for (int off = 1; off < 64; off <<= 1) {
    float t0 = __shfl_up(a0, off, 64);
    float t1 = __shfl_up(a1, off, 64);
    if (lane >= off) { a0 += t0; a1 += t1; }
  }
  a1 += __shfl(a0, 63, 64);
  const float cl = __shfl(a1, 63, 64);
  if (tid == 0) dtot[blk] = __expf(cl);

  f32x4 acc[4][2];   // [mt over d][ntl over this wave's 32 s-cols]
#pragma unroll
  for (int mt = 0; mt < 4; ++mt)
#pragma unroll
    for (int n = 0; n < 2; ++n) acc[mt][n] = (f32x4){0.f,0.f,0.f,0.f};

#pragma unroll 1
  for (int kt = 0; kt < 4; ++kt) {
    const int t0 = kt * 32;
    float dte[8];
#pragma unroll
    for (int j = 0; j < 8; ++j) {
      int p = t0 + g4 * 8 + j;
      float cs = __shfl(kt < 2 ? a0 : a1, p & 63, 64);
      dte[j] = __expf(cl - cs);
    }
    // A-frags: X^T rows = d (scalar strided global reads, split in reg)
    short8 xh[4], xl[4];
#pragma unroll
    for (int mt = 0; mt < 4; ++mt)
#pragma unroll
      for (int j = 0; j < 8; ++j) {
        float x = Xc[(size_t)(t0 + g4 * 8 + j) * DH + mt * 16 + l15];
        short h, l; bsplit(x, h, l);
        xh[mt][j] = h; xl[mt][j] = l;
      }
#pragma unroll
    for (int ntl = 0; ntl < 2; ++ntl) {
      const int scol = w32 + ntl * 16 + l15;
      short8 bh8, bl8;
#pragma unroll
      for (int j = 0; j < 8; ++j) {
        float bv = Bc[(size_t)(t0 + g4 * 8 + j) * DS + scol] * dte[j];
        short h, l; bsplit(bv, h, l);
        bh8[j] = h; bl8[j] = l;
      }
#pragma unroll
      for (int mt = 0; mt < 4; ++mt) {
        acc[mt][ntl] = __builtin_amdgcn_mfma_f32_16x16x32_bf16(xh[mt], bh8, acc[mt][ntl], 0, 0, 0);
        acc[mt][ntl] = __builtin_amdgcn_mfma_f32_16x16x32_bf16(xh[mt], bl8, acc[mt][ntl], 0, 0, 0);
        acc[mt][ntl] = __builtin_amdgcn_mfma_f32_16x16x32_bf16(xl[mt], bh8, acc[mt][ntl], 0, 0, 0);
      }
    }
  }
  // D layout: col = lane&15 (s), row = (lane>>4)*4 + r (d). store hT[d][s]
#pragma unroll
  for (int mt = 0; mt < 4; ++mt)
#pragma unroll
    for (int ntl = 0; ntl < 2; ++ntl)
#pragma unroll
      for (int r = 0; r < 4; ++r)
        hout[(size_t)(mt * 16 + g4 * 4 + r) * DS + w32 + ntl * 16 + l15] = acc[mt][ntl][r];
}

// ---------------- Phase 2: scan over chunks (hbuf is transposed [d][s]; h0/hfinal are [s][d]) ----------------
__global__ __launch_bounds__(256) void p2_scan(
    const float* __restrict__ h0, const float* __restrict__ dtot,
    float* __restrict__ hbuf, float* __restrict__ hfinal)
{
  int g = blockIdx.x * 256 + threadIdx.x;   // 0 .. 524287
  int bh = g >> 13;
  int e  = g & 8191;                        // e = d*128 + s  (hbuf layout)
  int d  = e >> 7, sidx = e & 127;
  size_t h0i = (size_t)bh * 8192 + sidx * 64 + d;
  float s = h0[h0i];
  const float* dt = dtot + bh * NC;
  float* p = hbuf + (size_t)bh * NC * 8192 + e;
#pragma unroll 1
  for (int cc = 0; cc < NC; ++cc) {
    float hc = p[(size_t)cc * 8192];
    p[(size_t)cc * 8192] = s;               // state at START of chunk cc
    s = fmaf(dt[cc], s, hc);
  }
  hfinal[h0i] = s;
}

// ---------------- Phase 3: Y = (L .* C B^T) X + diag(exp(csum)) C h   (MFMA bf16x3, zero barriers) ----------------
__global__ __launch_bounds__(256, 3) void p3_y(
    const float* __restrict__ A, const float* __restrict__ X,
    const float* __restrict__ B, const float* __restrict__ C,
    const float* __restrict__ hbuf, float* __restrict__ Y)
{
  __shared__ short Thi[128 * 40];   // 10240 B, row stride 80 B (16B-aligned)
  __shared__ short Tlo[128 * 40];   // 10240 B

  const int blk = blockIdx.x;
  const int bh  = blk >> 5;
  const int c   = blk & 31;
  const int tid = threadIdx.x;
  const int lane = tid & 63, w = tid >> 6;
  const int g4 = lane >> 4, l15 = lane & 15;
  const int w32 = w * 32;

  const float* Ac = A + bh * SEQ + c * CS;
  const float* Xc = X + (size_t)(bh * SEQ + c * CS) * DH;
  const float* Bc = B + (size_t)(bh * SEQ + c * CS) * DS;
  const float* Cc = C + (size_t)(bh * SEQ + c * CS) * DS;
  const float* hst = hbuf + (size_t)blk * DS * DH;   // [DH][DS] transposed
  float* Yc = Y + (size_t)(bh * SEQ + c * CS) * DH;

  // wave-level inclusive cumsum (no LDS, no barriers)
  float a0 = Ac[lane], a1 = Ac[64 + lane];
#pragma unroll
  for (int off = 1; off < 64; off <<= 1) {
    float t0 = __shfl_up(a0, off, 64);
    float t1 = __shfl_up(a1, off, 64);
    if (lane >= off) { a0 += t0; a1 += t1; }
  }
  a1 += __shfl(a0, 63, 64);

  f32x4 accCB[2][8];   // full 128x128 CB, this wave's 32 rows
  f32x4 accY[2][4];    // accumulates C*h, then decayed, then += T*X
#pragma unroll
  for (int mt = 0; mt < 2; ++mt) {
#pragma unroll
    for (int n = 0; n < 8; ++n) accCB[mt][n] = (f32x4){0.f,0.f,0.f,0.f};
#pragma unroll
    for (int n = 0; n < 4; ++n) accY[mt][n] = (f32x4){0.f,0.f,0.f,0.f};
  }

  // ---- fused K-loop: CB = C*B^T  and  Ch = C*h (K = state dim s), operands direct from global ----
#pragma unroll 1
  for (int kt = 0; kt < 4; ++kt) {
    const int k0 = kt * 32 + g4 * 8;
    short8 ah[2], al[2];
#pragma unroll
    for (int mt = 0; mt < 2; ++mt) {
      const float* cp = Cc + (size_t)(w32 + mt * 16 + l15) * DS + k0;
      split8(*(const float4*)cp, *(const float4*)(cp + 4), ah[mt], al[mt]);
    }
#pragma unroll
    for (int nt = 0; nt < 8; ++nt) {
      const float* bp = Bc + (size_t)(nt * 16 + l15) * DS + k0;
      short8 bh8, bl8;
      split8(*(const float4*)bp, *(const float4*)(bp + 4), bh8, bl8);
#pragma unroll
      for (int mt = 0; mt < 2; ++mt) {
        accCB[mt][nt] = __builtin_amdgcn_mfma_f32_16x16x32_bf16(ah[mt], bh8, accCB[mt][nt], 0, 0, 0);
        accCB[mt][nt] = __builtin_amdgcn_mfma_f32_16x16x32_bf16(ah[mt], bl8, accCB[mt][nt], 0, 0, 0);
        accCB[mt][nt] = __builtin_amdgcn_mfma_f32_16x16x32_bf16(al[mt], bh8, accCB[mt][nt], 0, 0, 0);
      }
    }
#pragma unroll
    for (int nd = 0; nd < 4; ++nd) {
      const float* hp = hst + (size_t)(nd * 16 + l15) * DS + k0;
      short8 hh8, hl8;
      split8(*(const float4*)hp, *(const float4*)(hp + 4), hh8, hl8);
#pragma unroll
      for (int mt = 0; mt < 2; ++mt) {
        accY[mt][nd] = __builtin_amdgcn_mfma_f32_16x16x32_bf16(ah[mt], hh8, accY[mt][nd], 0, 0, 0);
        accY[mt][nd] = __builtin_amdgcn_mfma_f32_16x16x32_bf16(ah[mt], hl8, accY[mt][nd], 0, 0, 0);
        accY[mt][nd] = __builtin_amdgcn_mfma_f32_16x16x32_bf16(al[mt], hh8, accY[mt][nd], 0, 0, 0);
      }
    }
  }

  // row cumsums for this wave's 32 output rows, and Y_inter scale exp(csum[i])
  float csI[2][4];
#pragma unroll
  for (int mt = 0; mt < 2; ++mt) {
    const float src = (w32 + mt * 16) < 64 ? a0 : a1;   // wave-uniform select
#pragma unroll
    for (int r = 0; r < 4; ++r) {
      int p = w32 + mt * 16 + g4 * 4 + r;
      csI[mt][r] = __shfl(src, p & 63, 64);
    }
  }
#pragma unroll
  for (int mt = 0; mt < 2; ++mt)
#pragma unroll
    for (int r = 0; r < 4; ++r) {
      float ei = __expf(csI[mt][r]);
#pragma unroll
      for (int nd = 0; nd < 4; ++nd) accY[mt][nd][r] *= ei;
    }

  // ---- intra: per 32-col slab of T = mask(L .* CB): regs -> LDS (wave-local rows) -> MFMA with X ----
#pragma unroll
  for (int jt = 0; jt < 4; ++jt) {
#pragma unroll
    for (int ntb = 0; ntb < 2; ++ntb) {
      const int nt = jt * 2 + ntb;
      const int jj = ntb * 16 + l15;
      const int j  = jt * 32 + jj;
      const float csj = __shfl(jt < 2 ? a0 : a1, j & 63, 64);
#pragma unroll
      for (int mt = 0; mt < 2; ++mt)
#pragma unroll
        for (int r = 0; r < 4; ++r) {
          int i = w32 + mt * 16 + g4 * 4 + r;
          float v = (i >= j) ? accCB[mt][nt][r] * __expf(csI[mt][r] - csj) : 0.f;
          short h, l; bsplit(v, h, l);
          Thi[i * 40 + jj] = h;
          Tlo[i * 40 + jj] = l;
        }
    }
    // T write->read is wave-local (each wave reads only its own 32 rows): no barrier.
    short8 th[2], tl[2];
#pragma unroll
    for (int mt = 0; mt < 2; ++mt) {
      th[mt] = *(const short8*)(Thi + (w32 + mt * 16 + l15) * 40 + g4 * 8);
      tl[mt] = *(const short8*)(Tlo + (w32 + mt * 16 + l15) * 40 + g4 * 8);
    }
#pragma unroll
    for (int nd = 0; nd < 4; ++nd) {
      short8 xh8, xl8;
#pragma unroll
      for (int jq = 0; jq < 8; ++jq) {
        float x = Xc[(size_t)(jt * 32 + g4 * 8 + jq) * DH + nd * 16 + l15];
        short h, l; bsplit(x, h, l);
        xh8[jq] = h; xl8[jq] = l;
      }
#pragma unroll
      for (int mt = 0; mt < 2; ++mt) {
        accY[mt][nd] = __builtin_amdgcn_mfma_f32_16x16x32_bf16(th[mt], xh8, accY[mt][nd], 0, 0, 0);
        accY[mt][nd] = __builtin_amdgcn_mfma_f32_16x16x32_bf16(th[mt], xl8, accY[mt][nd], 0, 0, 0);
        accY[mt][nd] = __builtin_amdgcn_mfma_f32_16x16x32_bf16(tl[mt], xh8, accY[mt][nd], 0, 0, 0);
      }
    }
  }

#pragma unroll
  for (int mt = 0; mt < 2; ++mt)
#pragma unroll
    for (int nd = 0; nd < 4; ++nd)
#pragma unroll
      for (int r = 0; r < 4; ++r)
        Yc[(size_t)(w32 + mt * 16 + g4 * 4 + r) * DH + nd * 16 + l15] = accY[mt][nd][r];
}

extern "C" void kernel_launch(void* const* d_in, const int* in_sizes, int n_in,
                              void* d_out, int out_size, void* d_ws, size_t ws_size,
                              hipStream_t stream)
{
  const float* X  = (const float*)d_in[0];
  const float* A  = (const float*)d_in[1];
  const float* B  = (const float*)d_in[2];
  const float* C  = (const float*)d_in[3];
  const float* h0 = (const float*)d_in[4];

  float* Y      = (float*)d_out;
  float* hfinal = Y + (size_t)NBH * SEQ * DH;

  float* hbuf = (float*)d_ws;                          // 64*32*8192 floats (transposed [d][s] per chunk)
  float* dtot = hbuf + (size_t)NBH * NC * DS * DH;     // 2048 floats

  dim3 blk(256);
  p1_hcontrib<<<dim3(NBH * NC), blk, 0, stream>>>(A, X, B, hbuf, dtot);
  p2_scan<<<dim3((NBH * DS * DH) / 256), blk, 0, stream>>>(h0, dtot, hbuf, hfinal);
  p3_y<<<dim3(NBH * NC), blk, 0, stream>>>(A, X, B, C, hbuf, Y);
}